// Round 1
// baseline (284.178 us; speedup 1.0000x reference)
//
#include <hip/hip_runtime.h>
#include <hip/hip_bf16.h>

#define NN 20000
#define NE 320000
#define XST 256   // xcat row stride (floats)
#define PST 128   // P row stride (floats): [0:64]=Pa, [64:128]=Pb

// ---- init: copy x into xcat[:,0:64], zero deg ----
__global__ __launch_bounds__(256) void init_kernel(const float* __restrict__ x,
                                                   float* __restrict__ xcat,
                                                   int* __restrict__ deg) {
    int i = blockIdx.x * 256 + threadIdx.x;
    if (i < NN * 16) {
        int n = i >> 4, c4 = (i & 15) << 2;
        float4 v = *(const float4*)(x + (size_t)n * 64 + c4);
        *(float4*)(xcat + (size_t)n * XST + c4) = v;
    }
    if (i < NN) deg[i] = 0;
}

// ---- CSR build ----
__global__ __launch_bounds__(256) void hist_kernel(const int* __restrict__ dst,
                                                   int* __restrict__ deg) {
    int i = blockIdx.x * 256 + threadIdx.x;
    if (i < NE) atomicAdd(deg + dst[i], 1);
}

__global__ __launch_bounds__(256) void scan_kernel(const int* __restrict__ deg,
                                                   int* __restrict__ rowptr,
                                                   int* __restrict__ cursor) {
    __shared__ int sums[256];
    int tid = threadIdx.x;
    const int CH = (NN + 255) / 256;  // 79
    int base = tid * CH;
    int s = 0;
    for (int i = 0; i < CH; ++i) {
        int idx = base + i;
        if (idx < NN) s += deg[idx];
    }
    sums[tid] = s;
    __syncthreads();
    for (int off = 1; off < 256; off <<= 1) {
        int t = (tid >= off) ? sums[tid - off] : 0;
        __syncthreads();
        sums[tid] += t;
        __syncthreads();
    }
    int run = sums[tid] - s;  // exclusive prefix of this thread's chunk
    for (int i = 0; i < CH; ++i) {
        int idx = base + i;
        if (idx < NN) {
            rowptr[idx] = run;
            cursor[idx] = run;
            run += deg[idx];
        }
    }
    if (tid == 255) rowptr[NN] = sums[255];
}

__global__ __launch_bounds__(256) void fill_kernel(const int* __restrict__ src,
                                                   const int* __restrict__ dst,
                                                   int* __restrict__ cursor,
                                                   int* __restrict__ elist) {
    int i = blockIdx.x * 256 + threadIdx.x;
    if (i < NE) {
        int p = atomicAdd(cursor + dst[i], 1);
        elist[p] = src[i];
    }
}

// ---- GEMM: P[:,0:64] = Xc[:,:C] @ (Wtop-Wbot);  P[:,64:128] = Xc[:,:C] @ Wbot
// W is [2C, 64] row-major. Tile: 64 rows x 128 cols per WG, 256 threads,
// thread tile 4 rows x 8 cols, K-chunk 64.
__global__ __launch_bounds__(256) void gemm_kernel(const float* __restrict__ xcat,
                                                   const float* __restrict__ W,
                                                   float* __restrict__ P, int C) {
    __shared__ float Xs[64][65];    // transposed: Xs[k][r]
    __shared__ float Ws[64][128];   // Ws[k][j]
    int tid = threadIdx.x;
    int tx = tid & 15, ty = tid >> 4;
    int r0 = blockIdx.x * 64;

    float acc[4][8];
#pragma unroll
    for (int i = 0; i < 4; ++i)
#pragma unroll
        for (int j = 0; j < 8; ++j) acc[i][j] = 0.f;

    for (int kk = 0; kk < C; kk += 64) {
        // load X tile (64 rows x 64 k), store transposed
#pragma unroll
        for (int q = 0; q < 4; ++q) {
            int f = tid + q * 256;      // float4 id 0..1023
            int row = f >> 4;           // 16 float4 per row
            int c4 = (f & 15) << 2;
            int gr = r0 + row;
            float4 v = make_float4(0.f, 0.f, 0.f, 0.f);
            if (gr < NN) v = *(const float4*)(xcat + (size_t)gr * XST + kk + c4);
            Xs[c4 + 0][row] = v.x;
            Xs[c4 + 1][row] = v.y;
            Xs[c4 + 2][row] = v.z;
            Xs[c4 + 3][row] = v.w;
        }
        // load + transform W tile (64 k x 128 j)
#pragma unroll
        for (int q = 0; q < 32; ++q) {
            int f = tid + q * 256;      // 0..8191
            int k = f >> 7;
            int j = f & 127;
            int gk = kk + k;
            float w;
            if (j < 64) w = W[(size_t)gk * 64 + j] - W[(size_t)(C + gk) * 64 + j];
            else        w = W[(size_t)(C + gk) * 64 + (j - 64)];
            Ws[k][j] = w;
        }
        __syncthreads();
#pragma unroll 8
        for (int k = 0; k < 64; ++k) {
            float4 xv = *(const float4*)&Xs[k][ty * 4];
            float4 w0 = *(const float4*)&Ws[k][tx * 8];
            float4 w1 = *(const float4*)&Ws[k][tx * 8 + 4];
            float xs[4] = {xv.x, xv.y, xv.z, xv.w};
            float wsv[8] = {w0.x, w0.y, w0.z, w0.w, w1.x, w1.y, w1.z, w1.w};
#pragma unroll
            for (int i = 0; i < 4; ++i)
#pragma unroll
                for (int j = 0; j < 8; ++j) acc[i][j] = fmaf(xs[i], wsv[j], acc[i][j]);
        }
        __syncthreads();
    }
#pragma unroll
    for (int i = 0; i < 4; ++i) {
        int gr = r0 + ty * 4 + i;
        if (gr < NN) {
            float4 o0 = make_float4(acc[i][0], acc[i][1], acc[i][2], acc[i][3]);
            float4 o1 = make_float4(acc[i][4], acc[i][5], acc[i][6], acc[i][7]);
            *(float4*)(P + (size_t)gr * PST + tx * 8) = o0;
            *(float4*)(P + (size_t)gr * PST + tx * 8 + 4) = o1;
        }
    }
}

// ---- aggregation: one wave per node; lane = channel.
// xcat[d, outoff+ch] = relu(Pa[d,ch] + b[ch] + max_{e in CSR[d]} Pb[src_e, ch])
__global__ __launch_bounds__(256) void agg_kernel(const float* __restrict__ P,
                                                  const float* __restrict__ b,
                                                  const int* __restrict__ rowptr,
                                                  const int* __restrict__ elist,
                                                  float* __restrict__ xcat, int outoff) {
    int wid = (int)((blockIdx.x * 256 + threadIdx.x) >> 6);
    int lane = threadIdx.x & 63;
    if (wid >= NN) return;
    int beg = rowptr[wid], end = rowptr[wid + 1];
    float m = -INFINITY;
    for (int idx = beg; idx < end; ++idx) {
        int s = elist[idx];
        m = fmaxf(m, P[(size_t)s * PST + 64 + lane]);
    }
    float v = P[(size_t)wid * PST + lane] + b[lane] + m;
    xcat[(size_t)wid * XST + outoff + lane] = fmaxf(v, 0.f);
}

// ---- final: out[n,g] = max over xcat[n, 4g..4g+3] ----
__global__ __launch_bounds__(256) void final_kernel(const float* __restrict__ xcat,
                                                    float* __restrict__ out) {
    int i = blockIdx.x * 256 + threadIdx.x;
    if (i < NN * 64) {
        int n = i >> 6, g = i & 63;
        float4 v = *(const float4*)(xcat + (size_t)n * XST + (g << 2));
        out[i] = fmaxf(fmaxf(v.x, v.y), fmaxf(v.z, v.w));
    }
}

extern "C" void kernel_launch(void* const* d_in, const int* in_sizes, int n_in,
                              void* d_out, int out_size, void* d_ws, size_t ws_size,
                              hipStream_t stream) {
    const float* x = (const float*)d_in[0];
    const float* Wp[3] = {(const float*)d_in[1], (const float*)d_in[3], (const float*)d_in[5]};
    const float* bp[3] = {(const float*)d_in[2], (const float*)d_in[4], (const float*)d_in[6]};
    const int* eidx = (const int*)d_in[7];
    const int* esrc = eidx;         // edge_index[0]
    const int* edst = eidx + NE;    // edge_index[1]
    float* out = (float*)d_out;

    float* xcat = (float*)d_ws;                       // 20000*256 f32
    float* P = xcat + (size_t)NN * XST;               // 20000*128 f32
    int* deg = (int*)(P + (size_t)NN * PST);          // 20000
    int* rowptr = deg + NN;                           // 20001
    int* cursor = rowptr + (NN + 1);                  // 20000
    int* elist = cursor + NN;                         // 320000

    init_kernel<<<(NN * 16 + 255) / 256, 256, 0, stream>>>(x, xcat, deg);
    hist_kernel<<<(NE + 255) / 256, 256, 0, stream>>>(edst, deg);
    scan_kernel<<<1, 256, 0, stream>>>(deg, rowptr, cursor);
    fill_kernel<<<(NE + 255) / 256, 256, 0, stream>>>(esrc, edst, cursor, elist);

    for (int blk = 0; blk < 3; ++blk) {
        int C = 64 + 64 * blk;
        gemm_kernel<<<(NN + 63) / 64, 256, 0, stream>>>(xcat, Wp[blk], P, C);
        agg_kernel<<<(NN + 3) / 4, 256, 0, stream>>>(P, bp[blk], rowptr, elist, xcat,
                                                     64 * (blk + 1));
    }
    final_kernel<<<(NN * 64 + 255) / 256, 256, 0, stream>>>(xcat, out);
}

// Round 2
// 180.946 us; speedup vs baseline: 1.5705x; 1.5705x over previous
//
#include <hip/hip_runtime.h>
#include <hip/hip_bf16.h>

#define NN 20000
#define NE 320000
#define XST 256   // xcat row stride (floats)
#define PST 128   // P row stride (floats): [0:64]=Pa, [64:128]=Pb
#define NBLK 79   // ceil(NN/256)

// ---- init: copy x into xcat[:,0:64], zero deg ----
__global__ __launch_bounds__(256) void init_kernel(const float* __restrict__ x,
                                                   float* __restrict__ xcat,
                                                   int* __restrict__ deg) {
    int i = blockIdx.x * 256 + threadIdx.x;
    if (i < NN * 16) {
        int n = i >> 4, c4 = (i & 15) << 2;
        float4 v = *(const float4*)(x + (size_t)n * 64 + c4);
        *(float4*)(xcat + (size_t)n * XST + c4) = v;
    }
    if (i < NN) deg[i] = 0;
}

__global__ __launch_bounds__(256) void hist_kernel(const int* __restrict__ dst,
                                                   int* __restrict__ deg) {
    int i = blockIdx.x * 256 + threadIdx.x;
    if (i < NE) atomicAdd(deg + dst[i], 1);
}

// ---- scan pass 1: per-block sums (coalesced) ----
__global__ __launch_bounds__(256) void scan1_kernel(const int* __restrict__ deg,
                                                    int* __restrict__ bsum) {
    __shared__ int red[4];
    int tid = threadIdx.x;
    int idx = blockIdx.x * 256 + tid;
    int v = (idx < NN) ? deg[idx] : 0;
#pragma unroll
    for (int off = 32; off > 0; off >>= 1) v += __shfl_down(v, off);
    if ((tid & 63) == 0) red[tid >> 6] = v;
    __syncthreads();
    if (tid == 0) bsum[blockIdx.x] = red[0] + red[1] + red[2] + red[3];
}

// ---- scan pass 2: scan the 79 block sums ----
__global__ __launch_bounds__(128) void scan2_kernel(const int* __restrict__ bsum,
                                                    int* __restrict__ boff,
                                                    int* __restrict__ rowptr) {
    __shared__ int s[128];
    int tid = threadIdx.x;
    int v = (tid < NBLK) ? bsum[tid] : 0;
    s[tid] = v;
    __syncthreads();
    for (int off = 1; off < 128; off <<= 1) {
        int t = (tid >= off) ? s[tid - off] : 0;
        __syncthreads();
        s[tid] += t;
        __syncthreads();
    }
    if (tid < NBLK) boff[tid] = s[tid] - v;       // exclusive
    if (tid == NBLK - 1) rowptr[NN] = s[tid];     // total
}

// ---- scan pass 3: block-local scan + offset -> rowptr, cursor ----
__global__ __launch_bounds__(256) void scan3_kernel(const int* __restrict__ deg,
                                                    const int* __restrict__ boff,
                                                    int* __restrict__ rowptr,
                                                    int* __restrict__ cursor) {
    __shared__ int s[256];
    int tid = threadIdx.x;
    int idx = blockIdx.x * 256 + tid;
    int v = (idx < NN) ? deg[idx] : 0;
    s[tid] = v;
    __syncthreads();
    for (int off = 1; off < 256; off <<= 1) {
        int t = (tid >= off) ? s[tid - off] : 0;
        __syncthreads();
        s[tid] += t;
        __syncthreads();
    }
    if (idx < NN) {
        int rp = boff[blockIdx.x] + s[tid] - v;   // exclusive
        rowptr[idx] = rp;
        cursor[idx] = rp;
    }
}

__global__ __launch_bounds__(256) void fill_kernel(const int* __restrict__ src,
                                                   const int* __restrict__ dst,
                                                   int* __restrict__ cursor,
                                                   int* __restrict__ elist) {
    int i = blockIdx.x * 256 + threadIdx.x;
    if (i < NE) {
        int p = atomicAdd(cursor + dst[i], 1);
        elist[p] = src[i];
    }
}

// ---- GEMM v2: P[:, cb*64 .. cb*64+63] over K=C.
//  cb=0: X @ (Wtop - Wbot)   cb=1: X @ Wbot
//  Tile: 32 rows x 64 cols, 256 threads, thread-tile 2 rows (ty, ty+16) x 4 cols.
//  Grid: (625, 2).
__global__ __launch_bounds__(256) void gemm2_kernel(const float* __restrict__ xcat,
                                                    const float* __restrict__ W,
                                                    float* __restrict__ P, int C) {
    __shared__ float Xs[64][33];   // [k][row]
    __shared__ float Ws[64][64];   // [k][j]
    int tid = threadIdx.x;
    int tx = tid & 15, ty = tid >> 4;
    int r0 = blockIdx.x * 32;
    int cb = blockIdx.y;

    float acc[2][4];
#pragma unroll
    for (int i = 0; i < 2; ++i)
#pragma unroll
        for (int j = 0; j < 4; ++j) acc[i][j] = 0.f;

    for (int kk = 0; kk < C; kk += 64) {
        // stage X tile: 32 rows x 64 k = 512 float4
#pragma unroll
        for (int q = 0; q < 2; ++q) {
            int fid = tid + q * 256;
            int row = fid >> 4, c4 = (fid & 15) << 2;
            float4 v = *(const float4*)(xcat + (size_t)(r0 + row) * XST + kk + c4);
            Xs[c4 + 0][row] = v.x;
            Xs[c4 + 1][row] = v.y;
            Xs[c4 + 2][row] = v.z;
            Xs[c4 + 3][row] = v.w;
        }
        // stage W tile: 64 k x 64 j = 1024 float4 (with transform for cb=0)
#pragma unroll
        for (int q = 0; q < 4; ++q) {
            int fid = tid + q * 256;
            int k = fid >> 4, c4 = (fid & 15) << 2;
            int gk = kk + k;
            float4 wb = *(const float4*)(W + (size_t)(C + gk) * 64 + c4);
            float4 wv;
            if (cb == 0) {
                float4 wt = *(const float4*)(W + (size_t)gk * 64 + c4);
                wv = make_float4(wt.x - wb.x, wt.y - wb.y, wt.z - wb.z, wt.w - wb.w);
            } else {
                wv = wb;
            }
            *(float4*)&Ws[k][c4] = wv;
        }
        __syncthreads();
#pragma unroll 8
        for (int k = 0; k < 64; ++k) {
            float x0 = Xs[k][ty];
            float x1 = Xs[k][ty + 16];
            float4 wv = *(const float4*)&Ws[k][tx << 2];
            acc[0][0] = fmaf(x0, wv.x, acc[0][0]);
            acc[0][1] = fmaf(x0, wv.y, acc[0][1]);
            acc[0][2] = fmaf(x0, wv.z, acc[0][2]);
            acc[0][3] = fmaf(x0, wv.w, acc[0][3]);
            acc[1][0] = fmaf(x1, wv.x, acc[1][0]);
            acc[1][1] = fmaf(x1, wv.y, acc[1][1]);
            acc[1][2] = fmaf(x1, wv.z, acc[1][2]);
            acc[1][3] = fmaf(x1, wv.w, acc[1][3]);
        }
        __syncthreads();
    }
    float* p0 = P + (size_t)(r0 + ty) * PST + cb * 64 + (tx << 2);
    *(float4*)p0 = make_float4(acc[0][0], acc[0][1], acc[0][2], acc[0][3]);
    float* p1 = P + (size_t)(r0 + ty + 16) * PST + cb * 64 + (tx << 2);
    *(float4*)p1 = make_float4(acc[1][0], acc[1][1], acc[1][2], acc[1][3]);
}

// ---- aggregation: one wave per node; lane = channel ----
__global__ __launch_bounds__(256) void agg_kernel(const float* __restrict__ P,
                                                  const float* __restrict__ b,
                                                  const int* __restrict__ rowptr,
                                                  const int* __restrict__ elist,
                                                  float* __restrict__ xcat, int outoff) {
    int wid = (int)((blockIdx.x * 256 + threadIdx.x) >> 6);
    int lane = threadIdx.x & 63;
    if (wid >= NN) return;
    int beg = rowptr[wid], end = rowptr[wid + 1];
    float m = -INFINITY;
    for (int idx = beg; idx < end; ++idx) {
        int s = elist[idx];
        m = fmaxf(m, P[(size_t)s * PST + 64 + lane]);
    }
    float v = P[(size_t)wid * PST + lane] + b[lane] + m;
    xcat[(size_t)wid * XST + outoff + lane] = fmaxf(v, 0.f);
}

// ---- final: out[n,g] = max over xcat[n, 4g..4g+3] ----
__global__ __launch_bounds__(256) void final_kernel(const float* __restrict__ xcat,
                                                    float* __restrict__ out) {
    int i = blockIdx.x * 256 + threadIdx.x;
    if (i < NN * 64) {
        int n = i >> 6, g = i & 63;
        float4 v = *(const float4*)(xcat + (size_t)n * XST + (g << 2));
        out[i] = fmaxf(fmaxf(v.x, v.y), fmaxf(v.z, v.w));
    }
}

extern "C" void kernel_launch(void* const* d_in, const int* in_sizes, int n_in,
                              void* d_out, int out_size, void* d_ws, size_t ws_size,
                              hipStream_t stream) {
    const float* x = (const float*)d_in[0];
    const float* Wp[3] = {(const float*)d_in[1], (const float*)d_in[3], (const float*)d_in[5]};
    const float* bp[3] = {(const float*)d_in[2], (const float*)d_in[4], (const float*)d_in[6]};
    const int* eidx = (const int*)d_in[7];
    const int* esrc = eidx;
    const int* edst = eidx + NE;
    float* out = (float*)d_out;

    float* xcat = (float*)d_ws;                       // 20000*256 f32
    float* P = xcat + (size_t)NN * XST;               // 20000*128 f32
    int* deg = (int*)(P + (size_t)NN * PST);          // 20000
    int* rowptr = deg + NN;                           // 20001
    int* cursor = rowptr + (NN + 1);                  // 20000
    int* elist = cursor + NN;                         // 320000
    int* bsum = elist + NE;                           // 79
    int* boff = bsum + NBLK;                          // 79

    init_kernel<<<(NN * 16 + 255) / 256, 256, 0, stream>>>(x, xcat, deg);
    hist_kernel<<<(NE + 255) / 256, 256, 0, stream>>>(edst, deg);
    scan1_kernel<<<NBLK, 256, 0, stream>>>(deg, bsum);
    scan2_kernel<<<1, 128, 0, stream>>>(bsum, boff, rowptr);
    scan3_kernel<<<NBLK, 256, 0, stream>>>(deg, boff, rowptr, cursor);
    fill_kernel<<<(NE + 255) / 256, 256, 0, stream>>>(esrc, edst, cursor, elist);

    for (int blk = 0; blk < 3; ++blk) {
        int C = 64 + 64 * blk;
        dim3 grid((NN + 31) / 32, 2);
        gemm2_kernel<<<grid, 256, 0, stream>>>(xcat, Wp[blk], P, C);
        agg_kernel<<<(NN + 3) / 4, 256, 0, stream>>>(P, bp[blk], rowptr, elist, xcat,
                                                     64 * (blk + 1));
    }
    final_kernel<<<(NN * 64 + 255) / 256, 256, 0, stream>>>(xcat, out);
}

// Round 3
// 157.351 us; speedup vs baseline: 1.8060x; 1.1499x over previous
//
#include <hip/hip_runtime.h>
#include <hip/hip_bf16.h>

#define NN 20000
#define NE 320000
#define XSTB 256    // xcatb row stride (bf16 elems)
#define NBLK 79     // ceil(NN/256)

typedef __attribute__((ext_vector_type(8))) short short8v;
typedef __attribute__((ext_vector_type(4))) float float4v;

struct bh4 { __hip_bfloat16 a, b, c, d; };  // 8-byte bf16 quad

// Wt layout: per layer, [128][K] bf16 row-major.
//   rows 0..63  : (Wtop - Wbot)^T  (col j, k)  -> Pa
//   rows 64..127: Wbot^T                        -> Pb
#define WT_OFF0 0
#define WT_OFF1 (128 * 64)
#define WT_OFF2 (128 * 64 + 128 * 128)
#define WT_TOT  (128 * 64 + 128 * 128 + 128 * 192)  // 49152

// ---- prep: x->bf16 xcat, build Wt (all 3 layers), zero deg ----
__global__ __launch_bounds__(256) void prep_kernel(const float* __restrict__ x,
                                                   const float* __restrict__ W0,
                                                   const float* __restrict__ W1,
                                                   const float* __restrict__ W2,
                                                   __hip_bfloat16* __restrict__ xcatb,
                                                   __hip_bfloat16* __restrict__ Wt,
                                                   int* __restrict__ deg) {
    int blk = blockIdx.x, tid = threadIdx.x;
    if (blk < 1250) {                       // x conversion: 320000 quads
        int i = blk * 256 + tid;
        int n = i >> 4, c4 = (i & 15) << 2;
        float4 v = *(const float4*)(x + (size_t)n * 64 + c4);
        bh4 o = {__float2bfloat16(v.x), __float2bfloat16(v.y),
                 __float2bfloat16(v.z), __float2bfloat16(v.w)};
        *(bh4*)(xcatb + (size_t)n * XSTB + c4) = o;
    } else if (blk < 1250 + 192) {          // Wt build: 49152 elems
        int e = (blk - 1250) * 256 + tid;
        const float* W;
        int K, off;
        if (e < WT_OFF1) { W = W0; K = 64;  off = WT_OFF0; }
        else if (e < WT_OFF2) { W = W1; K = 128; off = WT_OFF1; }
        else { W = W2; K = 192; off = WT_OFF2; }
        int el = e - off;
        int j = el / K, k = el - j * K;
        float w;
        if (j < 64) w = W[(size_t)k * 64 + j] - W[(size_t)(K + k) * 64 + j];
        else        w = W[(size_t)(K + k) * 64 + (j - 64)];
        Wt[(size_t)off + (size_t)j * K + k] = __float2bfloat16(w);
    } else {                                // deg zero
        int idx = (blk - 1442) * 256 + tid;
        if (idx < NN) deg[idx] = 0;
    }
}

__global__ __launch_bounds__(256) void hist_kernel(const int* __restrict__ dst,
                                                   int* __restrict__ deg) {
    int i = blockIdx.x * 256 + threadIdx.x;
    if (i < NE) atomicAdd(deg + dst[i], 1);
}

__global__ __launch_bounds__(256) void scan1_kernel(const int* __restrict__ deg,
                                                    int* __restrict__ bsum) {
    __shared__ int red[4];
    int tid = threadIdx.x;
    int idx = blockIdx.x * 256 + tid;
    int v = (idx < NN) ? deg[idx] : 0;
#pragma unroll
    for (int off = 32; off > 0; off >>= 1) v += __shfl_down(v, off);
    if ((tid & 63) == 0) red[tid >> 6] = v;
    __syncthreads();
    if (tid == 0) bsum[blockIdx.x] = red[0] + red[1] + red[2] + red[3];
}

__global__ __launch_bounds__(128) void scan2_kernel(const int* __restrict__ bsum,
                                                    int* __restrict__ boff,
                                                    int* __restrict__ rowptr) {
    __shared__ int s[128];
    int tid = threadIdx.x;
    int v = (tid < NBLK) ? bsum[tid] : 0;
    s[tid] = v;
    __syncthreads();
    for (int off = 1; off < 128; off <<= 1) {
        int t = (tid >= off) ? s[tid - off] : 0;
        __syncthreads();
        s[tid] += t;
        __syncthreads();
    }
    if (tid < NBLK) boff[tid] = s[tid] - v;
    if (tid == NBLK - 1) rowptr[NN] = s[tid];
}

__global__ __launch_bounds__(256) void scan3_kernel(const int* __restrict__ deg,
                                                    const int* __restrict__ boff,
                                                    int* __restrict__ rowptr,
                                                    int* __restrict__ cursor) {
    __shared__ int s[256];
    int tid = threadIdx.x;
    int idx = blockIdx.x * 256 + tid;
    int v = (idx < NN) ? deg[idx] : 0;
    s[tid] = v;
    __syncthreads();
    for (int off = 1; off < 256; off <<= 1) {
        int t = (tid >= off) ? s[tid - off] : 0;
        __syncthreads();
        s[tid] += t;
        __syncthreads();
    }
    if (idx < NN) {
        int rp = boff[blockIdx.x] + s[tid] - v;
        rowptr[idx] = rp;
        cursor[idx] = rp;
    }
}

__global__ __launch_bounds__(256) void fill_kernel(const int* __restrict__ src,
                                                   const int* __restrict__ dst,
                                                   int* __restrict__ cursor,
                                                   int* __restrict__ elist) {
    int i = blockIdx.x * 256 + threadIdx.x;
    if (i < NE) {
        int p = atomicAdd(cursor + dst[i], 1);
        elist[p] = src[i];
    }
}

// ---- MFMA GEMM: per wave, 16 rows x 64 cols. half=0 -> Pa (f32), half=1 -> Pb (bf16).
// A frag: lane l holds X[r0 + (l&15)][k0 + (l>>4)*8 + j], j=0..7
// B frag: lane l holds Wt_row[half*64 + t*16 + (l&15)], k = k0 + (l>>4)*8 + j
// D:      D[r0 + (l>>4)*4 + r][half*64 + t*16 + (l&15)]
template <int C>
__global__ __launch_bounds__(256) void gemm3_kernel(const __hip_bfloat16* __restrict__ xcatb,
                                                    const __hip_bfloat16* __restrict__ Wt,
                                                    float* __restrict__ Pa,
                                                    __hip_bfloat16* __restrict__ Pbb) {
    int tid = threadIdx.x;
    int wid = blockIdx.x * 4 + (tid >> 6);   // 0..2499
    int lane = tid & 63;
    int panel = wid >> 1;                    // 0..1249
    int half = wid & 1;
    int m = lane & 15, g = lane >> 4;
    const __hip_bfloat16* aptr = xcatb + (size_t)(panel * 16 + m) * XSTB + g * 8;
    const __hip_bfloat16* bptr = Wt + (size_t)(half * 64 + m) * C + g * 8;

    float4v acc[4] = {{0.f, 0.f, 0.f, 0.f}, {0.f, 0.f, 0.f, 0.f},
                      {0.f, 0.f, 0.f, 0.f}, {0.f, 0.f, 0.f, 0.f}};
#pragma unroll
    for (int k0 = 0; k0 < C; k0 += 32) {
        short8v a = *(const short8v*)(aptr + k0);
#pragma unroll
        for (int t = 0; t < 4; ++t) {
            short8v b = *(const short8v*)(bptr + (size_t)t * 16 * C + k0);
            acc[t] = __builtin_amdgcn_mfma_f32_16x16x32_bf16(a, b, acc[t], 0, 0, 0);
        }
    }
    int r0 = panel * 16;
    if (half == 0) {
#pragma unroll
        for (int t = 0; t < 4; ++t)
#pragma unroll
            for (int r = 0; r < 4; ++r)
                Pa[(size_t)(r0 + g * 4 + r) * 64 + t * 16 + m] = acc[t][r];
    } else {
#pragma unroll
        for (int t = 0; t < 4; ++t)
#pragma unroll
            for (int r = 0; r < 4; ++r)
                Pbb[(size_t)(r0 + g * 4 + r) * 64 + t * 16 + m] = __float2bfloat16(acc[t][r]);
    }
}

// ---- aggregation: one wave per node; lane = channel ----
__global__ __launch_bounds__(256) void agg_kernel(const float* __restrict__ Pa,
                                                  const __hip_bfloat16* __restrict__ Pbb,
                                                  const float* __restrict__ b,
                                                  const int* __restrict__ rowptr,
                                                  const int* __restrict__ elist,
                                                  __hip_bfloat16* __restrict__ xcatb,
                                                  int outoff) {
    int wid = (int)((blockIdx.x * 256 + threadIdx.x) >> 6);
    int lane = threadIdx.x & 63;
    if (wid >= NN) return;
    int beg = rowptr[wid], end = rowptr[wid + 1];
    float pa = Pa[(size_t)wid * 64 + lane] + b[lane];
    float mx = -INFINITY;
    for (int idx = beg; idx < end; ++idx) {
        int s = elist[idx];
        mx = fmaxf(mx, __bfloat162float(Pbb[(size_t)s * 64 + lane]));
    }
    float v = fmaxf(pa + mx, 0.f);
    xcatb[(size_t)wid * XSTB + outoff + lane] = __float2bfloat16(v);
}

// ---- final: out[n,g] = max over xcatb[n, 4g..4g+3] ----
__global__ __launch_bounds__(256) void final_kernel(const __hip_bfloat16* __restrict__ xcatb,
                                                    float* __restrict__ out) {
    int i = blockIdx.x * 256 + threadIdx.x;
    if (i < NN * 64) {
        int n = i >> 6, g = i & 63;
        bh4 v = *(const bh4*)(xcatb + (size_t)n * XSTB + (g << 2));
        float f0 = __bfloat162float(v.a), f1 = __bfloat162float(v.b);
        float f2 = __bfloat162float(v.c), f3 = __bfloat162float(v.d);
        out[i] = fmaxf(fmaxf(f0, f1), fmaxf(f2, f3));
    }
}

extern "C" void kernel_launch(void* const* d_in, const int* in_sizes, int n_in,
                              void* d_out, int out_size, void* d_ws, size_t ws_size,
                              hipStream_t stream) {
    const float* x = (const float*)d_in[0];
    const float* W0 = (const float*)d_in[1];
    const float* W1 = (const float*)d_in[3];
    const float* W2 = (const float*)d_in[5];
    const float* bp[3] = {(const float*)d_in[2], (const float*)d_in[4], (const float*)d_in[6]};
    const int* eidx = (const int*)d_in[7];
    const int* esrc = eidx;
    const int* edst = eidx + NE;
    float* out = (float*)d_out;

    char* w = (char*)d_ws;
    __hip_bfloat16* xcatb = (__hip_bfloat16*)w;            w += (size_t)NN * XSTB * 2;   // 10.24 MB
    float* Pa = (float*)w;                                 w += (size_t)NN * 64 * 4;     // 5.12 MB
    __hip_bfloat16* Pbb = (__hip_bfloat16*)w;              w += (size_t)NN * 64 * 2;     // 2.56 MB
    __hip_bfloat16* Wt = (__hip_bfloat16*)w;               w += (size_t)WT_TOT * 2;      // 96 KB
    int* deg = (int*)w;                                    w += (size_t)NN * 4;
    int* rowptr = (int*)w;                                 w += (size_t)(NN + 1) * 4;
    int* cursor = (int*)w;                                 w += (size_t)NN * 4;
    int* elist = (int*)w;                                  w += (size_t)NE * 4;
    int* bsum = (int*)w;                                   w += (size_t)NBLK * 4;
    int* boff = (int*)w;

    prep_kernel<<<1250 + 192 + 79, 256, 0, stream>>>(x, W0, W1, W2, xcatb, Wt, deg);
    hist_kernel<<<(NE + 255) / 256, 256, 0, stream>>>(edst, deg);
    scan1_kernel<<<NBLK, 256, 0, stream>>>(deg, bsum);
    scan2_kernel<<<1, 128, 0, stream>>>(bsum, boff, rowptr);
    scan3_kernel<<<NBLK, 256, 0, stream>>>(deg, boff, rowptr, cursor);
    fill_kernel<<<(NE + 255) / 256, 256, 0, stream>>>(esrc, edst, cursor, elist);

    const size_t wtoffs[3] = {WT_OFF0, WT_OFF1, WT_OFF2};
    for (int blk = 0; blk < 3; ++blk) {
        if (blk == 0)
            gemm3_kernel<64><<<625, 256, 0, stream>>>(xcatb, Wt + wtoffs[0], Pa, Pbb);
        else if (blk == 1)
            gemm3_kernel<128><<<625, 256, 0, stream>>>(xcatb, Wt + wtoffs[1], Pa, Pbb);
        else
            gemm3_kernel<192><<<625, 256, 0, stream>>>(xcatb, Wt + wtoffs[2], Pa, Pbb);
        agg_kernel<<<(NN + 3) / 4, 256, 0, stream>>>(Pa, Pbb, bp[blk], rowptr, elist,
                                                     xcatb, 64 * (blk + 1));
    }
    final_kernel<<<(NN * 64 + 255) / 256, 256, 0, stream>>>(xcatb, out);
}

// Round 4
// 108.684 us; speedup vs baseline: 2.6147x; 1.4478x over previous
//
#include <hip/hip_runtime.h>
#include <hip/hip_bf16.h>

#define NN 20000
#define NE 320000
#define XSTB 256    // xcatb row stride (bf16 elems)
#define CAP 96      // per-node edge bucket capacity (Poisson(16): P(>=96)~1e-47)

typedef __attribute__((ext_vector_type(8))) short short8v;
typedef __attribute__((ext_vector_type(4))) float float4v;

struct bh4 { __hip_bfloat16 a, b, c, d; };  // 8-byte bf16 quad

// Wt layout: per layer, [128][K] bf16 row-major.
//   rows 0..63  : (Wtop - Wbot)^T -> Pa
//   rows 64..127: Wbot^T          -> Pb
#define WT_OFF0 0
#define WT_OFF1 (128 * 64)
#define WT_OFF2 (128 * 64 + 128 * 128)
#define WT_TOT  (128 * 64 + 128 * 128 + 128 * 192)  // 49152 elems

// ---- prep: x->bf16 xcat, build Wt (all 3 layers), zero cursor ----
__global__ __launch_bounds__(256) void prep_kernel(const float* __restrict__ x,
                                                   const float* __restrict__ W0,
                                                   const float* __restrict__ W1,
                                                   const float* __restrict__ W2,
                                                   __hip_bfloat16* __restrict__ xcatb,
                                                   __hip_bfloat16* __restrict__ Wt,
                                                   int* __restrict__ cursor) {
    int blk = blockIdx.x, tid = threadIdx.x;
    if (blk < 1250) {                       // x conversion: 320000 quads exactly
        int i = blk * 256 + tid;
        int n = i >> 4, c4 = (i & 15) << 2;
        float4 v = *(const float4*)(x + (size_t)n * 64 + c4);
        bh4 o = {__float2bfloat16(v.x), __float2bfloat16(v.y),
                 __float2bfloat16(v.z), __float2bfloat16(v.w)};
        *(bh4*)(xcatb + (size_t)n * XSTB + c4) = o;
    } else if (blk < 1250 + 192) {          // Wt build: 49152 elems exactly
        int e = (blk - 1250) * 256 + tid;
        const float* W;
        int K, off;
        if (e < WT_OFF1) { W = W0; K = 64;  off = WT_OFF0; }
        else if (e < WT_OFF2) { W = W1; K = 128; off = WT_OFF1; }
        else { W = W2; K = 192; off = WT_OFF2; }
        int el = e - off;
        int j = el / K, k = el - j * K;
        float w;
        if (j < 64) w = W[(size_t)k * 64 + j] - W[(size_t)(K + k) * 64 + j];
        else        w = W[(size_t)(K + k) * 64 + (j - 64)];
        Wt[(size_t)off + (size_t)j * K + k] = __float2bfloat16(w);
    } else {                                // cursor zero
        int idx = (blk - 1442) * 256 + tid;
        if (idx < NN) cursor[idx] = 0;
    }
}

// ---- bucket CSR fill: elist[d*CAP + pos] = src ----
__global__ __launch_bounds__(256) void fillb_kernel(const int* __restrict__ src,
                                                    const int* __restrict__ dst,
                                                    int* __restrict__ cursor,
                                                    int* __restrict__ elist) {
    int i = blockIdx.x * 256 + threadIdx.x;
    if (i < NE) {
        int d = dst[i];
        int pos = atomicAdd(cursor + d, 1);
        if (pos < CAP) elist[(size_t)d * CAP + pos] = src[i];
    }
}

// ---- MFMA GEMM: per wave, 16 rows x 64 cols. half=0 -> Pa (f32), half=1 -> Pb (bf16).
template <int C>
__global__ __launch_bounds__(256) void gemm3_kernel(const __hip_bfloat16* __restrict__ xcatb,
                                                    const __hip_bfloat16* __restrict__ Wt,
                                                    float* __restrict__ Pa,
                                                    __hip_bfloat16* __restrict__ Pbb) {
    int tid = threadIdx.x;
    int wid = blockIdx.x * 4 + (tid >> 6);   // 0..2499
    int lane = tid & 63;
    int panel = wid >> 1;                    // 0..1249
    int half = wid & 1;
    int m = lane & 15, g = lane >> 4;
    const __hip_bfloat16* aptr = xcatb + (size_t)(panel * 16 + m) * XSTB + g * 8;
    const __hip_bfloat16* bptr = Wt + (size_t)(half * 64 + m) * C + g * 8;

    float4v acc[4] = {{0.f, 0.f, 0.f, 0.f}, {0.f, 0.f, 0.f, 0.f},
                      {0.f, 0.f, 0.f, 0.f}, {0.f, 0.f, 0.f, 0.f}};
#pragma unroll
    for (int k0 = 0; k0 < C; k0 += 32) {
        short8v a = *(const short8v*)(aptr + k0);
#pragma unroll
        for (int t = 0; t < 4; ++t) {
            short8v b = *(const short8v*)(bptr + (size_t)t * 16 * C + k0);
            acc[t] = __builtin_amdgcn_mfma_f32_16x16x32_bf16(a, b, acc[t], 0, 0, 0);
        }
    }
    int r0 = panel * 16;
    if (half == 0) {
#pragma unroll
        for (int t = 0; t < 4; ++t)
#pragma unroll
            for (int r = 0; r < 4; ++r)
                Pa[(size_t)(r0 + g * 4 + r) * 64 + t * 16 + m] = acc[t][r];
    } else {
#pragma unroll
        for (int t = 0; t < 4; ++t)
#pragma unroll
            for (int r = 0; r < 4; ++r)
                Pbb[(size_t)(r0 + g * 4 + r) * 64 + t * 16 + m] = __float2bfloat16(acc[t][r]);
    }
}

__device__ __forceinline__ float bucket_max(const int* __restrict__ el, int c, int lane,
                                            const __hip_bfloat16* __restrict__ Pbb) {
    float mx = -INFINITY;
    int i = 0;
    for (; i + 4 <= c; i += 4) {
        int s0 = el[i], s1 = el[i + 1], s2 = el[i + 2], s3 = el[i + 3];
        float v0 = __bfloat162float(Pbb[(size_t)s0 * 64 + lane]);
        float v1 = __bfloat162float(Pbb[(size_t)s1 * 64 + lane]);
        float v2 = __bfloat162float(Pbb[(size_t)s2 * 64 + lane]);
        float v3 = __bfloat162float(Pbb[(size_t)s3 * 64 + lane]);
        mx = fmaxf(mx, fmaxf(fmaxf(v0, v1), fmaxf(v2, v3)));
    }
    for (; i < c; ++i) {
        int s = el[i];
        mx = fmaxf(mx, __bfloat162float(Pbb[(size_t)s * 64 + lane]));
    }
    return mx;
}

// ---- aggregation (layers 0,1): one wave per node; lane = channel ----
__global__ __launch_bounds__(256) void agg_kernel(const float* __restrict__ Pa,
                                                  const __hip_bfloat16* __restrict__ Pbb,
                                                  const float* __restrict__ b,
                                                  const int* __restrict__ cnt,
                                                  const int* __restrict__ elist,
                                                  __hip_bfloat16* __restrict__ xcatb,
                                                  int outoff) {
    int wid = (int)((blockIdx.x * 256 + threadIdx.x) >> 6);
    int lane = threadIdx.x & 63;
    int c = cnt[wid];
    if (c > CAP) c = CAP;
    float mx = bucket_max(elist + (size_t)wid * CAP, c, lane, Pbb);
    float v = fmaxf(Pa[(size_t)wid * 64 + lane] + b[lane] + mx, 0.f);
    xcatb[(size_t)wid * XSTB + outoff + lane] = __float2bfloat16(v);
}

// ---- last layer agg + final max, fused ----
__global__ __launch_bounds__(256) void aggf_kernel(const float* __restrict__ Pa,
                                                   const __hip_bfloat16* __restrict__ Pbb,
                                                   const float* __restrict__ b,
                                                   const int* __restrict__ cnt,
                                                   const int* __restrict__ elist,
                                                   const __hip_bfloat16* __restrict__ xcatb,
                                                   float* __restrict__ out) {
    __shared__ float sm[4][64];
    int w = threadIdx.x >> 6, lane = threadIdx.x & 63;
    int wid = blockIdx.x * 4 + w;            // 5000*4 = 20000 exactly
    int c = cnt[wid];
    if (c > CAP) c = CAP;
    float mx = bucket_max(elist + (size_t)wid * CAP, c, lane, Pbb);
    float v = fmaxf(Pa[(size_t)wid * 64 + lane] + b[lane] + mx, 0.f);
    sm[w][lane] = v;
    __syncthreads();
    float m;
    if (lane < 48) {
        bh4 q = *(const bh4*)(xcatb + (size_t)wid * XSTB + (lane << 2));
        float f0 = __bfloat162float(q.a), f1 = __bfloat162float(q.b);
        float f2 = __bfloat162float(q.c), f3 = __bfloat162float(q.d);
        m = fmaxf(fmaxf(f0, f1), fmaxf(f2, f3));
    } else {
        const float* p = &sm[w][(lane - 48) << 2];
        m = fmaxf(fmaxf(p[0], p[1]), fmaxf(p[2], p[3]));
    }
    out[(size_t)wid * 64 + lane] = m;
}

extern "C" void kernel_launch(void* const* d_in, const int* in_sizes, int n_in,
                              void* d_out, int out_size, void* d_ws, size_t ws_size,
                              hipStream_t stream) {
    const float* x = (const float*)d_in[0];
    const float* W0 = (const float*)d_in[1];
    const float* W1 = (const float*)d_in[3];
    const float* W2 = (const float*)d_in[5];
    const float* bp[3] = {(const float*)d_in[2], (const float*)d_in[4], (const float*)d_in[6]};
    const int* eidx = (const int*)d_in[7];
    const int* esrc = eidx;
    const int* edst = eidx + NE;
    float* out = (float*)d_out;

    char* w = (char*)d_ws;
    __hip_bfloat16* xcatb = (__hip_bfloat16*)w;  w += (size_t)NN * XSTB * 2;  // 10.24 MB
    float* Pa = (float*)w;                       w += (size_t)NN * 64 * 4;    // 5.12 MB
    __hip_bfloat16* Pbb = (__hip_bfloat16*)w;    w += (size_t)NN * 64 * 2;    // 2.56 MB
    __hip_bfloat16* Wt = (__hip_bfloat16*)w;     w += (size_t)WT_TOT * 2;     // 96 KB
    int* cursor = (int*)w;                       w += (size_t)NN * 4;         // 80 KB
    int* elist = (int*)w;                        /* NN*CAP*4 = 7.68 MB */

    prep_kernel<<<1250 + 192 + 79, 256, 0, stream>>>(x, W0, W1, W2, xcatb, Wt, cursor);
    fillb_kernel<<<(NE + 255) / 256, 256, 0, stream>>>(esrc, edst, cursor, elist);

    gemm3_kernel<64><<<625, 256, 0, stream>>>(xcatb, Wt + WT_OFF0, Pa, Pbb);
    agg_kernel<<<(NN + 3) / 4, 256, 0, stream>>>(Pa, Pbb, bp[0], cursor, elist, xcatb, 64);
    gemm3_kernel<128><<<625, 256, 0, stream>>>(xcatb, Wt + WT_OFF1, Pa, Pbb);
    agg_kernel<<<(NN + 3) / 4, 256, 0, stream>>>(Pa, Pbb, bp[1], cursor, elist, xcatb, 128);
    gemm3_kernel<192><<<625, 256, 0, stream>>>(xcatb, Wt + WT_OFF2, Pa, Pbb);
    aggf_kernel<<<(NN + 3) / 4, 256, 0, stream>>>(Pa, Pbb, bp[2], cursor, elist, xcatb, out);
}

// Round 5
// 96.956 us; speedup vs baseline: 2.9310x; 1.1210x over previous
//
#include <hip/hip_runtime.h>
#include <hip/hip_bf16.h>

#define NN 20000
#define NE 320000
#define XSTB 256    // xcatb row stride (bf16 elems)
#define CAP 96      // per-node edge bucket capacity (Poisson(16): P(>=96)~1e-47)

typedef __attribute__((ext_vector_type(8))) short short8v;
typedef __attribute__((ext_vector_type(4))) float float4v;

struct bh4 { __hip_bfloat16 a, b, c, d; };  // 8-byte bf16 quad

// Wt layout: per layer, [128][K] bf16 row-major.
//   rows 0..63  : (Wtop - Wbot)^T -> Pa
//   rows 64..127: Wbot^T          -> Pb
#define WT_OFF0 0
#define WT_OFF1 (128 * 64)
#define WT_OFF2 (128 * 64 + 128 * 128)
#define WT_TOT  (128 * 64 + 128 * 128 + 128 * 192)  // 49152 elems

// ---- prep: x->bf16 xcat, build Wt (all 3 layers), zero cursor ----
__global__ __launch_bounds__(256) void prep_kernel(const float* __restrict__ x,
                                                   const float* __restrict__ W0,
                                                   const float* __restrict__ W1,
                                                   const float* __restrict__ W2,
                                                   __hip_bfloat16* __restrict__ xcatb,
                                                   __hip_bfloat16* __restrict__ Wt,
                                                   int* __restrict__ cursor) {
    int blk = blockIdx.x, tid = threadIdx.x;
    if (blk < 1250) {                       // x conversion: 320000 quads exactly
        int i = blk * 256 + tid;
        int n = i >> 4, c4 = (i & 15) << 2;
        float4 v = *(const float4*)(x + (size_t)n * 64 + c4);
        bh4 o = {__float2bfloat16(v.x), __float2bfloat16(v.y),
                 __float2bfloat16(v.z), __float2bfloat16(v.w)};
        *(bh4*)(xcatb + (size_t)n * XSTB + c4) = o;
    } else if (blk < 1250 + 192) {          // Wt build: 49152 elems exactly
        int e = (blk - 1250) * 256 + tid;
        const float* W;
        int K, off;
        if (e < WT_OFF1) { W = W0; K = 64;  off = WT_OFF0; }
        else if (e < WT_OFF2) { W = W1; K = 128; off = WT_OFF1; }
        else { W = W2; K = 192; off = WT_OFF2; }
        int el = e - off;
        int j = el / K, k = el - j * K;
        float w;
        if (j < 64) w = W[(size_t)k * 64 + j] - W[(size_t)(K + k) * 64 + j];
        else        w = W[(size_t)(K + k) * 64 + (j - 64)];
        Wt[(size_t)off + (size_t)j * K + k] = __float2bfloat16(w);
    } else {                                // cursor zero
        int idx = (blk - 1442) * 256 + tid;
        if (idx < NN) cursor[idx] = 0;
    }
}

// ---- bucket CSR fill ----
__global__ __launch_bounds__(256) void fillb_kernel(const int* __restrict__ src,
                                                    const int* __restrict__ dst,
                                                    int* __restrict__ cursor,
                                                    int* __restrict__ elist) {
    int i = blockIdx.x * 256 + threadIdx.x;
    if (i < NE) {
        int d = dst[i];
        int pos = atomicAdd(cursor + d, 1);
        if (pos < CAP) elist[(size_t)d * CAP + pos] = src[i];
    }
}

// ---- layer-0 GEMM (K=64): per wave 16 rows x 64 cols; half=0->Pa f32, half=1->Pb bf16
__global__ __launch_bounds__(256) void gemm0_kernel(const __hip_bfloat16* __restrict__ xcatb,
                                                    const __hip_bfloat16* __restrict__ Wt,
                                                    float* __restrict__ Pa,
                                                    __hip_bfloat16* __restrict__ Pbb) {
    int tid = threadIdx.x;
    int wid = blockIdx.x * 4 + (tid >> 6);
    int lane = tid & 63;
    int panel = wid >> 1, half = wid & 1;
    int m = lane & 15, g = lane >> 4;
    const __hip_bfloat16* aptr = xcatb + (size_t)(panel * 16 + m) * XSTB + g * 8;
    const __hip_bfloat16* bptr = Wt + (size_t)(half * 64 + m) * 64 + g * 8;

    float4v acc[4] = {{0.f,0.f,0.f,0.f},{0.f,0.f,0.f,0.f},{0.f,0.f,0.f,0.f},{0.f,0.f,0.f,0.f}};
#pragma unroll
    for (int k0 = 0; k0 < 64; k0 += 32) {
        short8v a = *(const short8v*)(aptr + k0);
#pragma unroll
        for (int t = 0; t < 4; ++t) {
            short8v b = *(const short8v*)(bptr + (size_t)t * 16 * 64 + k0);
            acc[t] = __builtin_amdgcn_mfma_f32_16x16x32_bf16(a, b, acc[t], 0, 0, 0);
        }
    }
    int r0 = panel * 16;
    if (half == 0) {
#pragma unroll
        for (int t = 0; t < 4; ++t)
#pragma unroll
            for (int r = 0; r < 4; ++r)
                Pa[(size_t)(r0 + g * 4 + r) * 64 + t * 16 + m] = acc[t][r];
    } else {
#pragma unroll
        for (int t = 0; t < 4; ++t)
#pragma unroll
            for (int r = 0; r < 4; ++r)
                Pbb[(size_t)(r0 + g * 4 + r) * 64 + t * 16 + m] = __float2bfloat16(acc[t][r]);
    }
}

__device__ __forceinline__ float bucket_max(const int* __restrict__ el, int c, int lane,
                                            const __hip_bfloat16* __restrict__ Pbb) {
    float mx = -INFINITY;
    int i = 0;
    for (; i + 4 <= c; i += 4) {
        int s0 = el[i], s1 = el[i + 1], s2 = el[i + 2], s3 = el[i + 3];
        float v0 = __bfloat162float(Pbb[(size_t)s0 * 64 + lane]);
        float v1 = __bfloat162float(Pbb[(size_t)s1 * 64 + lane]);
        float v2 = __bfloat162float(Pbb[(size_t)s2 * 64 + lane]);
        float v3 = __bfloat162float(Pbb[(size_t)s3 * 64 + lane]);
        mx = fmaxf(mx, fmaxf(fmaxf(v0, v1), fmaxf(v2, v3)));
    }
    for (; i < c; ++i) {
        int s = el[i];
        mx = fmaxf(mx, __bfloat162float(Pbb[(size_t)s * 64 + lane]));
    }
    return mx;
}

// ---- fused: agg(layer i) for 16 nodes -> LDS + xcatb, then gemm(layer i+1) K=C.
//  C = total K of next layer (128 or 192); new 64 channels (k in [C-64,C)) come from LDS.
//  outoff = C - 64 (where the new block lands in xcatb).
template <int C>
__global__ __launch_bounds__(256) void fused_kernel(const float* __restrict__ PaIn,
                                                    const __hip_bfloat16* __restrict__ PbbIn,
                                                    const float* __restrict__ b,
                                                    const int* __restrict__ cnt,
                                                    const int* __restrict__ elist,
                                                    __hip_bfloat16* __restrict__ xcatb,
                                                    const __hip_bfloat16* __restrict__ Wt,
                                                    float* __restrict__ PaOut,
                                                    __hip_bfloat16* __restrict__ PbbOut) {
    __shared__ __hip_bfloat16 newt[16][72];  // padded: <=2-way bank conflicts
    int tid = threadIdx.x;
    int w = tid >> 6, lane = tid & 63;
    int panel = blockIdx.x;
    int r0 = panel * 16;

    // ---- phase A: aggregate 4 nodes per wave ----
#pragma unroll
    for (int nl = 0; nl < 4; ++nl) {
        int local = w * 4 + nl;
        int node = r0 + local;
        int c = cnt[node];
        if (c > CAP) c = CAP;
        float mx = bucket_max(elist + (size_t)node * CAP, c, lane, PbbIn);
        float v = fmaxf(PaIn[(size_t)node * 64 + lane] + b[lane] + mx, 0.f);
        __hip_bfloat16 h = __float2bfloat16(v);
        newt[local][lane] = h;
        xcatb[(size_t)node * XSTB + (C - 64) + lane] = h;
    }
    __syncthreads();
    if (w >= 2) return;

    // ---- phase B: MFMA gemm for this panel, half = w ----
    int half = w;
    int m = lane & 15, g = lane >> 4;
    const __hip_bfloat16* aptr = xcatb + (size_t)(r0 + m) * XSTB + g * 8;
    const __hip_bfloat16* bptr = Wt + (size_t)(half * 64 + m) * C + g * 8;

    float4v acc[4] = {{0.f,0.f,0.f,0.f},{0.f,0.f,0.f,0.f},{0.f,0.f,0.f,0.f},{0.f,0.f,0.f,0.f}};
#pragma unroll
    for (int k0 = 0; k0 < C; k0 += 32) {
        short8v a;
        if (k0 < C - 64) a = *(const short8v*)(aptr + k0);
        else             a = *(const short8v*)(&newt[m][k0 - (C - 64) + g * 8]);
#pragma unroll
        for (int t = 0; t < 4; ++t) {
            short8v bb = *(const short8v*)(bptr + (size_t)t * 16 * C + k0);
            acc[t] = __builtin_amdgcn_mfma_f32_16x16x32_bf16(a, bb, acc[t], 0, 0, 0);
        }
    }
    if (half == 0) {
#pragma unroll
        for (int t = 0; t < 4; ++t)
#pragma unroll
            for (int r = 0; r < 4; ++r)
                PaOut[(size_t)(r0 + g * 4 + r) * 64 + t * 16 + m] = acc[t][r];
    } else {
#pragma unroll
        for (int t = 0; t < 4; ++t)
#pragma unroll
            for (int r = 0; r < 4; ++r)
                PbbOut[(size_t)(r0 + g * 4 + r) * 64 + t * 16 + m] = __float2bfloat16(acc[t][r]);
    }
}

// ---- last layer agg + final max, fused ----
__global__ __launch_bounds__(256) void aggf_kernel(const float* __restrict__ Pa,
                                                   const __hip_bfloat16* __restrict__ Pbb,
                                                   const float* __restrict__ b,
                                                   const int* __restrict__ cnt,
                                                   const int* __restrict__ elist,
                                                   const __hip_bfloat16* __restrict__ xcatb,
                                                   float* __restrict__ out) {
    __shared__ float sm[4][64];
    int w = threadIdx.x >> 6, lane = threadIdx.x & 63;
    int wid = blockIdx.x * 4 + w;
    int c = cnt[wid];
    if (c > CAP) c = CAP;
    float mx = bucket_max(elist + (size_t)wid * CAP, c, lane, Pbb);
    float v = fmaxf(Pa[(size_t)wid * 64 + lane] + b[lane] + mx, 0.f);
    sm[w][lane] = v;
    __syncthreads();
    float m;
    if (lane < 48) {
        bh4 q = *(const bh4*)(xcatb + (size_t)wid * XSTB + (lane << 2));
        float f0 = __bfloat162float(q.a), f1 = __bfloat162float(q.b);
        float f2 = __bfloat162float(q.c), f3 = __bfloat162float(q.d);
        m = fmaxf(fmaxf(f0, f1), fmaxf(f2, f3));
    } else {
        const float* p = &sm[w][(lane - 48) << 2];
        m = fmaxf(fmaxf(p[0], p[1]), fmaxf(p[2], p[3]));
    }
    out[(size_t)wid * 64 + lane] = m;
}

extern "C" void kernel_launch(void* const* d_in, const int* in_sizes, int n_in,
                              void* d_out, int out_size, void* d_ws, size_t ws_size,
                              hipStream_t stream) {
    const float* x = (const float*)d_in[0];
    const float* W0 = (const float*)d_in[1];
    const float* W1 = (const float*)d_in[3];
    const float* W2 = (const float*)d_in[5];
    const float* bp[3] = {(const float*)d_in[2], (const float*)d_in[4], (const float*)d_in[6]};
    const int* eidx = (const int*)d_in[7];
    const int* esrc = eidx;
    const int* edst = eidx + NE;
    float* out = (float*)d_out;

    char* w = (char*)d_ws;
    __hip_bfloat16* xcatb = (__hip_bfloat16*)w;  w += (size_t)NN * XSTB * 2;  // 10.24 MB
    float* PaA = (float*)w;                      w += (size_t)NN * 64 * 4;    // 5.12 MB
    __hip_bfloat16* PbbA = (__hip_bfloat16*)w;   w += (size_t)NN * 64 * 2;    // 2.56 MB
    float* PaB = (float*)w;                      w += (size_t)NN * 64 * 4;    // 5.12 MB
    __hip_bfloat16* PbbB = (__hip_bfloat16*)w;   w += (size_t)NN * 64 * 2;    // 2.56 MB
    __hip_bfloat16* Wt = (__hip_bfloat16*)w;     w += (size_t)WT_TOT * 2;     // 96 KB
    int* cursor = (int*)w;                       w += (size_t)NN * 4;         // 80 KB
    int* elist = (int*)w;                        /* NN*CAP*4 = 7.68 MB */

    prep_kernel<<<1250 + 192 + 79, 256, 0, stream>>>(x, W0, W1, W2, xcatb, Wt, cursor);
    fillb_kernel<<<(NE + 255) / 256, 256, 0, stream>>>(esrc, edst, cursor, elist);

    // layer0 GEMM -> PaA/PbbA
    gemm0_kernel<<<625, 256, 0, stream>>>(xcatb, Wt + WT_OFF0, PaA, PbbA);
    // agg0 + gemm1 (K=128) -> PaB/PbbB
    fused_kernel<128><<<1250, 256, 0, stream>>>(PaA, PbbA, bp[0], cursor, elist, xcatb,
                                                Wt + WT_OFF1, PaB, PbbB);
    // agg1 + gemm2 (K=192) -> PaA/PbbA
    fused_kernel<192><<<1250, 256, 0, stream>>>(PaB, PbbB, bp[1], cursor, elist, xcatb,
                                                Wt + WT_OFF2, PaA, PbbA);
    // agg2 + final
    aggf_kernel<<<(NN + 3) / 4, 256, 0, stream>>>(PaA, PbbA, bp[2], cursor, elist, xcatb, out);
}